// Round 9
// baseline (736.852 us; speedup 1.0000x reference)
//
#include <hip/hip_runtime.h>

#define N_NODES 100000
#define N_EDGES 3200000
#define SLOPE 0.01f

#define NBUCK 391              // ceil(100000/256) buckets of 256 dst nodes
#define NBLK_B 256             // one ghist column per block: exclusive append regions
#define EPB (N_EDGES / NBLK_B) // 12500 edges per block (exact)
#define NGH (NBUCK * NBLK_B)   // ghist/goff size = 100096
#define CAP_C 10240            // passC LDS buffer (bucket edges: mean 8192, sigma~90)

typedef __attribute__((ext_vector_type(8))) short short8;
typedef __attribute__((ext_vector_type(4))) float f32x4;

static inline size_t align_up(size_t x, size_t a){ return (x + a - 1) / a * a; }

__device__ inline unsigned short f2bf(float f){
  unsigned u = __float_as_uint(f);
  u += 0x7fffu + ((u >> 16) & 1u);
  return (unsigned short)(u >> 16);
}
__device__ inline float bf2f(unsigned short s){
  return __uint_as_float(((unsigned)s) << 16);
}
__device__ inline void add2(float& a0, float& a1, unsigned u){
  a0 += __uint_as_float(u << 16);
  a1 += __uint_as_float(u & 0xffff0000u);
}

// ---------------- CSR build (unchanged from round 8) ----------------

__global__ void gbhist_k(const int* __restrict__ dst, int* __restrict__ ghist){
  __shared__ int h[NBUCK];
  int tid = threadIdx.x, blk = blockIdx.x;
  for (int i = tid; i < NBUCK; i += 1024) h[i] = 0;
  __syncthreads();
  int e0 = blk * EPB;
  for (int e = e0 + tid; e < e0 + EPB; e += 1024) atomicAdd(&h[dst[e] >> 8], 1);
  __syncthreads();
  for (int i = tid; i < NBUCK; i += 1024) ghist[i * NBLK_B + blk] = h[i];
}

__global__ void scan1_k(const int* __restrict__ in, int* __restrict__ out,
                        int* __restrict__ bsums, int n){
  __shared__ int lds[256];
  int tid = threadIdx.x;
  int base = blockIdx.x * 1024 + tid * 4;
  int v0 = (base + 0 < n) ? in[base + 0] : 0;
  int v1 = (base + 1 < n) ? in[base + 1] : 0;
  int v2 = (base + 2 < n) ? in[base + 2] : 0;
  int v3 = (base + 3 < n) ? in[base + 3] : 0;
  int tsum = v0 + v1 + v2 + v3;
  lds[tid] = tsum;
  for (int off = 1; off < 256; off <<= 1){
    __syncthreads();
    int x = (tid >= off) ? lds[tid - off] : 0;
    __syncthreads();
    lds[tid] += x;
  }
  __syncthreads();
  int excl = lds[tid] - tsum;
  if (base + 0 < n) out[base + 0] = excl;
  if (base + 1 < n) out[base + 1] = excl + v0;
  if (base + 2 < n) out[base + 2] = excl + v0 + v1;
  if (base + 3 < n) out[base + 3] = excl + v0 + v1 + v2;
  if (tid == 255) bsums[blockIdx.x] = lds[255];
}

__global__ void scan2_k(int* bsums, int nb){
  int lane = threadIdx.x;
  int base = 0;
  for (int off = 0; off < nb; off += 64){
    int idx = off + lane;
    int v = (idx < nb) ? bsums[idx] : 0;
    int sc = v;
    for (int m = 1; m < 64; m <<= 1){
      int t = __shfl_up(sc, m);
      if (lane >= m) sc += t;
    }
    int total = __shfl(sc, 63);
    if (idx < nb) bsums[idx] = sc - v + base;
    base += total;
  }
}

__global__ void scan3_k(int* __restrict__ out, const int* __restrict__ bsums, int n){
  int i = blockIdx.x * 256 + threadIdx.x;
  if (i < n) out[i] += bsums[i >> 10];
}

__global__ void passB_k(const int* __restrict__ src, const int* __restrict__ dst,
                        const int* __restrict__ ghist, const int* __restrict__ goff,
                        int* __restrict__ pk){
  __shared__ int h[NBUCK];
  __shared__ int buf[EPB];     // 50KB
  int tid = threadIdx.x, blk = blockIdx.x;
  for (int i = tid; i < NBUCK; i += 1024) h[i] = ghist[i * NBLK_B + blk];
  __syncthreads();
  if (tid < 64){
    int base = 0;
    for (int off = 0; off < NBUCK; off += 64){
      int idx = off + tid;
      int v = (idx < NBUCK) ? h[idx] : 0;
      int sc = v;
      for (int m = 1; m < 64; m <<= 1){
        int t = __shfl_up(sc, m);
        if (tid >= m) sc += t;
      }
      int total = __shfl(sc, 63);
      if (idx < NBUCK) h[idx] = sc - v + base;
      base += total;
    }
  }
  __syncthreads();
  int e0 = blk * EPB;
  for (int e = e0 + tid; e < e0 + EPB; e += 1024){
    int d = dst[e];
    int p = atomicAdd(&h[d >> 8], 1);
    buf[p] = (src[e] << 8) | (d & 255);
  }
  __syncthreads();
  int wv = tid >> 6, ln = tid & 63;
  for (int b = wv; b < NBUCK; b += 16){
    int s0 = (b == 0) ? 0 : h[b - 1];
    int L  = h[b] - s0;
    int g0 = goff[b * NBLK_B + blk];
    for (int j = ln; j < L; j += 64) pk[g0 + j] = buf[s0 + j];
  }
}

__global__ void passC_k(const int* __restrict__ pk, const int* __restrict__ goff,
                        int* __restrict__ ssrc, int* __restrict__ row_ptr){
  __shared__ int cur[256];
  __shared__ int buf[CAP_C];   // 40KB
  int b = blockIdx.x, tid = threadIdx.x;   // 512 threads
  if (tid < 256) cur[tid] = 0;
  __syncthreads();
  int s = goff[b * NBLK_B];
  int e = (b == NBUCK - 1) ? N_EDGES : goff[(b + 1) * NBLK_B];
  int cnt = e - s;
  for (int i = s + tid; i < e; i += 512) atomicAdd(&cur[pk[i] & 255], 1);
  __syncthreads();
  if (tid < 64){
    int base = 0;
    for (int off = 0; off < 256; off += 64){
      int idx = off + tid;
      int v = cur[idx];
      int sc = v;
      for (int m = 1; m < 64; m <<= 1){
        int t = __shfl_up(sc, m);
        if (tid >= m) sc += t;
      }
      int total = __shfl(sc, 63);
      cur[idx] = sc - v + base;
      base += total;
    }
  }
  __syncthreads();
  int node = b * 256 + tid;
  if (tid < 256 && node < N_NODES) row_ptr[node] = s + cur[tid];
  if (b == NBUCK - 1 && tid == 0) row_ptr[N_NODES] = N_EDGES;
  __syncthreads();
  for (int i = s + tid; i < e; i += 512){
    int v = pk[i];
    int p = atomicAdd(&cur[v & 255], 1);
    if (p < CAP_C) buf[p] = v >> 8;
    else ssrc[s + p] = v >> 8;   // statistically unreachable safety
  }
  __syncthreads();
  int lim = (cnt < CAP_C) ? cnt : CAP_C;
  for (int i = tid; i < lim; i += 512) ssrc[s + i] = buf[i];
}

// ---------------- W2 fragment prep (once) ----------------
__global__ void wfrag_k(const float* __restrict__ W, unsigned short* __restrict__ Wfrag){
  int l = threadIdx.x;  // 64 threads
  int r = l & 15, g = l >> 4;
  for (int mb = 0; mb < 4; ++mb)
    for (int kt = 0; kt < 2; ++kt)
      for (int j = 0; j < 8; ++j){
        int k = kt * 32 + g * 8 + j;
        Wfrag[((mb * 2 + kt) * 64 + l) * 8 + j] = f2bf(W[k * 64 + mb * 16 + r]);
      }
}

// ---------------- Layer 1: feat[N,4] -> lrelu(agg @ W1 + b1) -> planes ----------
__global__ void conv1_k(const float* __restrict__ feat, const int* __restrict__ row_ptr,
                        const int* __restrict__ ssrc, const float* __restrict__ W1,
                        const float* __restrict__ b1,
                        unsigned short* __restrict__ outA, unsigned short* __restrict__ outB){
  int gt = blockIdx.x * 256 + threadIdx.x;
  int node = gt >> 6;
  int lane = threadIdx.x & 63;
  int s = row_ptr[node], t = row_ptr[node + 1];
  float a0 = 0.f, a1 = 0.f, a2 = 0.f, a3 = 0.f;
  for (int i = s + lane; i < t; i += 64){
    int nb = ssrc[i];
    const float4 v = *(const float4*)(feat + (size_t)nb * 4);
    a0 += v.x; a1 += v.y; a2 += v.z; a3 += v.w;
  }
  for (int m = 1; m < 64; m <<= 1){
    a0 += __shfl_xor(a0, m);
    a1 += __shfl_xor(a1, m);
    a2 += __shfl_xor(a2, m);
    a3 += __shfl_xor(a3, m);
  }
  float o = b1[lane] + a0 * W1[lane] + a1 * W1[64 + lane] + a2 * W1[128 + lane] + a3 * W1[192 + lane];
  o = (o > 0.f) ? o : SLOPE * o;
  if (lane < 32) outA[node * 32 + lane] = f2bf(o);
  else           outB[node * 32 + lane - 32] = f2bf(o);
}

// ---------------- Dense GEMM: (zA,zB) = x @ W2 from planes (bf16, MFMA) -------------
__global__ void mm64_k(const unsigned short* __restrict__ xA, const unsigned short* __restrict__ xB,
                       const unsigned short* __restrict__ Wfrag,
                       unsigned short* __restrict__ zA, unsigned short* __restrict__ zB){
  int lane = threadIdx.x & 63;
  int wid = (blockIdx.x * blockDim.x + threadIdx.x) >> 6;
  int nwaves = (gridDim.x * blockDim.x) >> 6;
  int r = lane & 15, g = lane >> 4;
  const short8* Wf = (const short8*)Wfrag;
  short8 Af[4][2];
  #pragma unroll
  for (int mb = 0; mb < 4; ++mb){
    Af[mb][0] = Wf[(mb * 2 + 0) * 64 + lane];
    Af[mb][1] = Wf[(mb * 2 + 1) * 64 + lane];
  }
  const int NT = N_NODES / 16;  // 6250
  for (int t = wid; t < NT; t += nwaves){
    int base = t * 16;
    const short8 B0 = *(const short8*)(xA + (size_t)(base + r) * 32 + g * 8);
    const short8 B1 = *(const short8*)(xB + (size_t)(base + r) * 32 + g * 8);
    #pragma unroll
    for (int mb = 0; mb < 4; ++mb){
      f32x4 c = {0.f, 0.f, 0.f, 0.f};
      c = __builtin_amdgcn_mfma_f32_16x16x32_bf16(Af[mb][0], B0, c, 0, 0, 0);
      c = __builtin_amdgcn_mfma_f32_16x16x32_bf16(Af[mb][1], B1, c, 0, 0, 0);
      ushort4 pk4;
      pk4.x = f2bf(c[0]); pk4.y = f2bf(c[1]); pk4.z = f2bf(c[2]); pk4.w = f2bf(c[3]);
      unsigned short* dst = (mb < 2)
        ? (zA + (size_t)(base + r) * 32 + mb * 16 + g * 4)
        : (zB + (size_t)(base + r) * 32 + (mb - 2) * 16 + g * 4);
      *(ushort4*)dst = pk4;
    }
  }
}

// ---------------- Half-plane aggregate: out_h = lrelu(agg(z_h) + b_h) ----------------
// One wave per node; 64B rows; uint2/lane, 8 lanes/row, 6 unconditional bursts
// (48 slots), masked accumulate, 3-level reduce. Round-4 proven shape on half rows.
__global__ void aggH_k(const unsigned short* __restrict__ z, const int* __restrict__ row_ptr,
                       const int* __restrict__ ssrc, const float* __restrict__ b32,
                       unsigned short* __restrict__ outp){
  int gt = blockIdx.x * 256 + threadIdx.x;
  int node = gt >> 6;
  int lane = threadIdx.x & 63;
  int s = row_ptr[node], cnt = row_ptr[node + 1] - s;
  int nb_l = ssrc[s + lane];          // coalesced; 64-int margin past N_EDGES zeroed
  int q = lane >> 3, o = lane & 7;
  const size_t oo = (size_t)(o << 2);  // 4 shorts = 8B per lane
  float a0=0.f,a1=0.f,a2=0.f,a3=0.f;
  uint2 v0, v1, v2, v3, v4, v5;
  int cm1 = (cnt > 0) ? cnt - 1 : 0;
  {
    int j0 = min( 0 + q, cm1), j1 = min( 8 + q, cm1), j2 = min(16 + q, cm1);
    int j3 = min(24 + q, cm1), j4 = min(32 + q, cm1), j5 = min(40 + q, cm1);
    int n0 = __shfl(nb_l, j0), n1 = __shfl(nb_l, j1), n2 = __shfl(nb_l, j2);
    int n3 = __shfl(nb_l, j3), n4 = __shfl(nb_l, j4), n5 = __shfl(nb_l, j5);
    v0 = *(const uint2*)(z + (size_t)n0 * 32 + oo);
    v1 = *(const uint2*)(z + (size_t)n1 * 32 + oo);
    v2 = *(const uint2*)(z + (size_t)n2 * 32 + oo);
    v3 = *(const uint2*)(z + (size_t)n3 * 32 + oo);
    v4 = *(const uint2*)(z + (size_t)n4 * 32 + oo);
    v5 = *(const uint2*)(z + (size_t)n5 * 32 + oo);
  }
  if ( 0 + q < cnt){ add2(a0,a1,v0.x); add2(a2,a3,v0.y); }
  if ( 8 + q < cnt){ add2(a0,a1,v1.x); add2(a2,a3,v1.y); }
  if (16 + q < cnt){ add2(a0,a1,v2.x); add2(a2,a3,v2.y); }
  if (24 + q < cnt){ add2(a0,a1,v3.x); add2(a2,a3,v3.y); }
  if (32 + q < cnt){ add2(a0,a1,v4.x); add2(a2,a3,v4.y); }
  if (40 + q < cnt){ add2(a0,a1,v5.x); add2(a2,a3,v5.y); }
  for (int i = 48 + q; i < cnt; i += 8){
    int nb = ssrc[s + i];
    uint2 vv = *(const uint2*)(z + (size_t)nb * 32 + oo);
    add2(a0,a1,vv.x); add2(a2,a3,vv.y);
  }
  for (int m = 8; m < 64; m <<= 1){
    a0 += __shfl_xor(a0, m); a1 += __shfl_xor(a1, m);
    a2 += __shfl_xor(a2, m); a3 += __shfl_xor(a3, m);
  }
  if (lane < 8){
    const float4 bb = *(const float4*)(b32 + lane * 4);
    float y0 = a0 + bb.x, y1 = a1 + bb.y, y2 = a2 + bb.z, y3 = a3 + bb.w;
    y0 = (y0 > 0.f) ? y0 : SLOPE * y0;  y1 = (y1 > 0.f) ? y1 : SLOPE * y1;
    y2 = (y2 > 0.f) ? y2 : SLOPE * y2;  y3 = (y3 > 0.f) ? y3 : SLOPE * y3;
    uint2 pkd;
    pkd.x = (unsigned)f2bf(y0) | ((unsigned)f2bf(y1) << 16);
    pkd.y = (unsigned)f2bf(y2) | ((unsigned)f2bf(y3) << 16);
    *(uint2*)(outp + (size_t)node * 32 + lane * 4) = pkd;
  }
}

// ---------------- Last layer: y4 = x @ W5 [N,4] (w=0), then agg + b5 ----------------
__global__ void premult_k(const unsigned short* __restrict__ xA, const unsigned short* __restrict__ xB,
                          const float* __restrict__ W5, float* __restrict__ y4){
  int gt = blockIdx.x * 256 + threadIdx.x;
  int node = gt >> 6;
  int lane = threadIdx.x & 63;
  float xv = (lane < 32) ? bf2f(xA[node * 32 + lane]) : bf2f(xB[node * 32 + lane - 32]);
  float p0 = xv * W5[lane * 3 + 0];
  float p1 = xv * W5[lane * 3 + 1];
  float p2 = xv * W5[lane * 3 + 2];
  for (int m = 1; m < 64; m <<= 1){
    p0 += __shfl_xor(p0, m);
    p1 += __shfl_xor(p1, m);
    p2 += __shfl_xor(p2, m);
  }
  if (lane == 0){
    float4 v; v.x = p0; v.y = p1; v.z = p2; v.w = 0.f;
    *(float4*)(y4 + (size_t)node * 4) = v;
  }
}

__global__ void agg3_k(const float* __restrict__ y4, const int* __restrict__ row_ptr,
                       const int* __restrict__ ssrc, const float* __restrict__ b5,
                       float* __restrict__ out){
  int gt = blockIdx.x * 256 + threadIdx.x;
  int node = gt >> 6;
  int lane = threadIdx.x & 63;
  int s = row_ptr[node], t = row_ptr[node + 1];
  int c = lane & 3;
  float acc = 0.f;
  for (int i = s + (lane >> 2); i < t; i += 16) acc += y4[(size_t)ssrc[i] * 4 + c];
  for (int m = 4; m < 64; m <<= 1) acc += __shfl_xor(acc, m);
  if (lane < 3) out[node * 3 + lane] = acc + b5[lane];
}

// ---------------- launch ----------------

extern "C" void kernel_launch(void* const* d_in, const int* in_sizes, int n_in,
                              void* d_out, int out_size, void* d_ws, size_t ws_size,
                              hipStream_t stream){
  const float* feat = (const float*)d_in[0];
  const int*   src  = (const int*)d_in[1];
  const int*   dst  = (const int*)d_in[2];
  const float* W1   = (const float*)d_in[3];
  const float* b1   = (const float*)d_in[4];
  const float* W2   = (const float*)d_in[5];
  const float* b2   = (const float*)d_in[6];
  const float* W5   = (const float*)d_in[7];
  const float* b5   = (const float*)d_in[8];
  float* out = (float*)d_out;

  char* p = (char*)d_ws;
  auto carve = [&](size_t bytes) -> char* {
    char* r = p; p += align_up(bytes, 512); return r;
  };
  int*   row_ptr = (int*)carve((size_t)(N_NODES + 1) * 4);
  int*   bsums   = (int*)carve(512 * 4);
  unsigned short* Wfrag = (unsigned short*)carve(4096 * 2);
  int*   ghist   = (int*)carve((size_t)NGH * 4);
  int*   goff    = (int*)carve((size_t)NGH * 4);
  int*   ssrc    = (int*)carve(((size_t)N_EDGES + 64) * 4);  // +64 margin
  unsigned short* fA0 = (unsigned short*)carve((size_t)N_NODES * 32 * 2);
  unsigned short* fB0 = (unsigned short*)carve((size_t)N_NODES * 32 * 2);
  unsigned short* fA1 = (unsigned short*)carve((size_t)N_NODES * 32 * 2);
  unsigned short* fB1 = (unsigned short*)carve((size_t)N_NODES * 32 * 2);
  float* y4      = (float*)carve((size_t)N_NODES * 4 * 4);
  int*   pk      = (int*)carve((size_t)N_EDGES * 4);
  // z planes alias pk (12.8MB >= 2 x 6.4MB): pk dead once passC completes
  unsigned short* zA = (unsigned short*)pk;
  unsigned short* zB = zA + (size_t)N_NODES * 32;

  // ---- CSR build ----
  gbhist_k<<<NBLK_B, 1024, 0, stream>>>(dst, ghist);
  {
    int nb = (NGH + 1023) / 1024;  // 98
    scan1_k<<<nb, 256, 0, stream>>>(ghist, goff, bsums, NGH);
    scan2_k<<<1, 64, 0, stream>>>(bsums, nb);
    scan3_k<<<(NGH + 255) / 256, 256, 0, stream>>>(goff, bsums, NGH);
  }
  passB_k<<<NBLK_B, 1024, 0, stream>>>(src, dst, ghist, goff, pk);
  passC_k<<<NBUCK, 512, 0, stream>>>(pk, goff, ssrc, row_ptr);
  hipMemsetAsync(ssrc + N_EDGES, 0, 64 * 4, stream);
  wfrag_k<<<1, 64, 0, stream>>>(W2, Wfrag);

  // ---- layers ----
  conv1_k<<<(N_NODES * 64) / 256, 256, 0, stream>>>(feat, row_ptr, ssrc, W1, b1, fA0, fB0);

  unsigned short *xinA = fA0, *xinB = fB0, *xoutA = fA1, *xoutB = fB1;
  for (int l = 0; l < 7; ++l){
    mm64_k<<<512, 256, 0, stream>>>(xinA, xinB, Wfrag, zA, zB);
    aggH_k<<<(N_NODES * 64) / 256, 256, 0, stream>>>(zA, row_ptr, ssrc, b2, xoutA);
    aggH_k<<<(N_NODES * 64) / 256, 256, 0, stream>>>(zB, row_ptr, ssrc, b2 + 32, xoutB);
    unsigned short* t;
    t = xinA; xinA = xoutA; xoutA = t;
    t = xinB; xinB = xoutB; xoutB = t;
  }

  premult_k<<<(N_NODES * 64) / 256, 256, 0, stream>>>(xinA, xinB, W5, y4);
  agg3_k<<<(N_NODES * 64) / 256, 256, 0, stream>>>(y4, row_ptr, ssrc, b5, out);
}

// Round 11
// 549.959 us; speedup vs baseline: 1.3398x; 1.3398x over previous
//
#include <hip/hip_runtime.h>

#define N_NODES 100000
#define N_EDGES 3200000
#define SLOPE 0.01f

#define NBUCK 391              // ceil(100000/256) buckets of 256 dst nodes
#define NBLK_B 256             // one ghist column per block: exclusive append regions
#define EPB (N_EDGES / NBLK_B) // 12500 edges per block (exact)
#define NGH (NBUCK * NBLK_B)   // ghist/goff size = 100096
#define CAP_C 10240            // passC LDS buffer (bucket edges: mean 8192, sigma~90)

typedef __attribute__((ext_vector_type(8))) short short8;
typedef __attribute__((ext_vector_type(4))) float f32x4;

static inline size_t align_up(size_t x, size_t a){ return (x + a - 1) / a * a; }

__device__ inline unsigned short f2bf(float f){
  unsigned u = __float_as_uint(f);
  u += 0x7fffu + ((u >> 16) & 1u);
  return (unsigned short)(u >> 16);
}
__device__ inline float bf2f(unsigned short s){
  return __uint_as_float(((unsigned)s) << 16);
}
__device__ inline void add2(float& a0, float& a1, unsigned u){
  a0 += __uint_as_float(u << 16);
  a1 += __uint_as_float(u & 0xffff0000u);
}

// ---------------- CSR build (round-8 proven) ----------------

__global__ void gbhist_k(const int* __restrict__ dst, int* __restrict__ ghist){
  __shared__ int h[NBUCK];
  int tid = threadIdx.x, blk = blockIdx.x;
  for (int i = tid; i < NBUCK; i += 1024) h[i] = 0;
  __syncthreads();
  int e0 = blk * EPB;
  for (int e = e0 + tid; e < e0 + EPB; e += 1024) atomicAdd(&h[dst[e] >> 8], 1);
  __syncthreads();
  for (int i = tid; i < NBUCK; i += 1024) ghist[i * NBLK_B + blk] = h[i];
}

__global__ void scan1_k(const int* __restrict__ in, int* __restrict__ out,
                        int* __restrict__ bsums, int n){
  __shared__ int lds[256];
  int tid = threadIdx.x;
  int base = blockIdx.x * 1024 + tid * 4;
  int v0 = (base + 0 < n) ? in[base + 0] : 0;
  int v1 = (base + 1 < n) ? in[base + 1] : 0;
  int v2 = (base + 2 < n) ? in[base + 2] : 0;
  int v3 = (base + 3 < n) ? in[base + 3] : 0;
  int tsum = v0 + v1 + v2 + v3;
  lds[tid] = tsum;
  for (int off = 1; off < 256; off <<= 1){
    __syncthreads();
    int x = (tid >= off) ? lds[tid - off] : 0;
    __syncthreads();
    lds[tid] += x;
  }
  __syncthreads();
  int excl = lds[tid] - tsum;
  if (base + 0 < n) out[base + 0] = excl;
  if (base + 1 < n) out[base + 1] = excl + v0;
  if (base + 2 < n) out[base + 2] = excl + v0 + v1;
  if (base + 3 < n) out[base + 3] = excl + v0 + v1 + v2;
  if (tid == 255) bsums[blockIdx.x] = lds[255];
}

__global__ void scan2_k(int* bsums, int nb){
  int lane = threadIdx.x;
  int base = 0;
  for (int off = 0; off < nb; off += 64){
    int idx = off + lane;
    int v = (idx < nb) ? bsums[idx] : 0;
    int sc = v;
    for (int m = 1; m < 64; m <<= 1){
      int t = __shfl_up(sc, m);
      if (lane >= m) sc += t;
    }
    int total = __shfl(sc, 63);
    if (idx < nb) bsums[idx] = sc - v + base;
    base += total;
  }
}

__global__ void scan3_k(int* __restrict__ out, const int* __restrict__ bsums, int n){
  int i = blockIdx.x * 256 + threadIdx.x;
  if (i < n) out[i] += bsums[i >> 10];
}

__global__ void passB_k(const int* __restrict__ src, const int* __restrict__ dst,
                        const int* __restrict__ ghist, const int* __restrict__ goff,
                        int* __restrict__ pk){
  __shared__ int h[NBUCK];
  __shared__ int buf[EPB];     // 50KB
  int tid = threadIdx.x, blk = blockIdx.x;
  for (int i = tid; i < NBUCK; i += 1024) h[i] = ghist[i * NBLK_B + blk];
  __syncthreads();
  if (tid < 64){
    int base = 0;
    for (int off = 0; off < NBUCK; off += 64){
      int idx = off + tid;
      int v = (idx < NBUCK) ? h[idx] : 0;
      int sc = v;
      for (int m = 1; m < 64; m <<= 1){
        int t = __shfl_up(sc, m);
        if (tid >= m) sc += t;
      }
      int total = __shfl(sc, 63);
      if (idx < NBUCK) h[idx] = sc - v + base;
      base += total;
    }
  }
  __syncthreads();
  int e0 = blk * EPB;
  for (int e = e0 + tid; e < e0 + EPB; e += 1024){
    int d = dst[e];
    int p = atomicAdd(&h[d >> 8], 1);
    buf[p] = (src[e] << 8) | (d & 255);
  }
  __syncthreads();
  int wv = tid >> 6, ln = tid & 63;
  for (int b = wv; b < NBUCK; b += 16){
    int s0 = (b == 0) ? 0 : h[b - 1];
    int L  = h[b] - s0;
    int g0 = goff[b * NBLK_B + blk];
    for (int j = ln; j < L; j += 64) pk[g0 + j] = buf[s0 + j];
  }
}

__global__ void passC_k(const int* __restrict__ pk, const int* __restrict__ goff,
                        int* __restrict__ ssrc, int* __restrict__ row_ptr){
  __shared__ int cur[256];
  __shared__ int buf[CAP_C];   // 40KB
  int b = blockIdx.x, tid = threadIdx.x;   // 512 threads
  if (tid < 256) cur[tid] = 0;
  __syncthreads();
  int s = goff[b * NBLK_B];
  int e = (b == NBUCK - 1) ? N_EDGES : goff[(b + 1) * NBLK_B];
  int cnt = e - s;
  for (int i = s + tid; i < e; i += 512) atomicAdd(&cur[pk[i] & 255], 1);
  __syncthreads();
  if (tid < 64){
    int base = 0;
    for (int off = 0; off < 256; off += 64){
      int idx = off + tid;
      int v = cur[idx];
      int sc = v;
      for (int m = 1; m < 64; m <<= 1){
        int t = __shfl_up(sc, m);
        if (tid >= m) sc += t;
      }
      int total = __shfl(sc, 63);
      cur[idx] = sc - v + base;
      base += total;
    }
  }
  __syncthreads();
  int node = b * 256 + tid;
  if (tid < 256 && node < N_NODES) row_ptr[node] = s + cur[tid];
  if (b == NBUCK - 1 && tid == 0) row_ptr[N_NODES] = N_EDGES;
  __syncthreads();
  for (int i = s + tid; i < e; i += 512){
    int v = pk[i];
    int p = atomicAdd(&cur[v & 255], 1);
    if (p < CAP_C) buf[p] = v >> 8;
    else ssrc[s + p] = v >> 8;   // statistically unreachable safety
  }
  __syncthreads();
  int lim = (cnt < CAP_C) ? cnt : CAP_C;
  for (int i = tid; i < lim; i += 512) ssrc[s + i] = buf[i];
}

// ---------------- W2 fragment prep (once) ----------------
__global__ void wfrag_k(const float* __restrict__ W, unsigned short* __restrict__ Wfrag){
  int l = threadIdx.x;  // 64 threads
  int r = l & 15, g = l >> 4;
  for (int mb = 0; mb < 4; ++mb)
    for (int kt = 0; kt < 2; ++kt)
      for (int j = 0; j < 8; ++j){
        int k = kt * 32 + g * 8 + j;
        Wfrag[((mb * 2 + kt) * 64 + l) * 8 + j] = f2bf(W[k * 64 + mb * 16 + r]);
      }
}

// ---------------- Layer 1: feat[N,4] -> lrelu(agg @ W1 + b1) -> bf16 [N,64] --------
__global__ void conv1_k(const float* __restrict__ feat, const int* __restrict__ row_ptr,
                        const int* __restrict__ ssrc, const float* __restrict__ W1,
                        const float* __restrict__ b1, unsigned short* __restrict__ out){
  int gt = blockIdx.x * 256 + threadIdx.x;
  int node = gt >> 6;
  int lane = threadIdx.x & 63;
  int s = row_ptr[node], t = row_ptr[node + 1];
  float a0 = 0.f, a1 = 0.f, a2 = 0.f, a3 = 0.f;
  for (int i = s + lane; i < t; i += 64){
    int nb = ssrc[i];
    const float4 v = *(const float4*)(feat + (size_t)nb * 4);
    a0 += v.x; a1 += v.y; a2 += v.z; a3 += v.w;
  }
  for (int m = 1; m < 64; m <<= 1){
    a0 += __shfl_xor(a0, m);
    a1 += __shfl_xor(a1, m);
    a2 += __shfl_xor(a2, m);
    a3 += __shfl_xor(a3, m);
  }
  float o = b1[lane] + a0 * W1[lane] + a1 * W1[64 + lane] + a2 * W1[128 + lane] + a3 * W1[192 + lane];
  o = (o > 0.f) ? o : SLOPE * o;
  out[node * 64 + lane] = f2bf(o);
}

// ---------------- Fused mid layer: x' = lrelu(agg(x) @ W2 + b2) -> bf16 -------------
// 16 waves = 16 nodes per block. Gather: one wave-uniform branch picks 4 bursts
// (cnt<=32, ~54% of nodes) or 6 bursts (+rare tail); each path keeps back-to-back
// load issue. Wave 0 then runs the 16x64x64 MFMA.
__global__ __launch_bounds__(1024) void aggmm_k(
    const unsigned short* __restrict__ x, const int* __restrict__ row_ptr,
    const int* __restrict__ ssrc, const unsigned short* __restrict__ Wfrag,
    const float* __restrict__ b, unsigned short* __restrict__ out){
  __shared__ unsigned short aggL[16][72];   // padded rows
  int tid = threadIdx.x;
  int w = tid >> 6, lane = tid & 63;
  int node = blockIdx.x * 16 + w;            // grid exactly N_NODES/16
  int s = row_ptr[node], cnt = row_ptr[node + 1] - s;
  int nb_l = ssrc[s + lane];                 // coalesced; margin past N_EDGES zeroed
  int q = lane >> 3, o = lane & 7;
  const size_t oo = (size_t)(o << 3);
  float a0=0.f,a1=0.f,a2=0.f,a3=0.f,a4=0.f,a5=0.f,a6=0.f,a7=0.f;
  int cm1 = (cnt > 0) ? cnt - 1 : 0;
  #define ACCM(V, base) if (base + q < cnt){ add2(a0,a1,V.x); add2(a2,a3,V.y); add2(a4,a5,V.z); add2(a6,a7,V.w); }
  if (cnt <= 32){
    uint4 v0, v1, v2, v3;
    {
      int j0 = min( 0 + q, cm1), j1 = min( 8 + q, cm1);
      int j2 = min(16 + q, cm1), j3 = min(24 + q, cm1);
      int n0 = __shfl(nb_l, j0), n1 = __shfl(nb_l, j1);
      int n2 = __shfl(nb_l, j2), n3 = __shfl(nb_l, j3);
      v0 = *(const uint4*)(x + (size_t)n0 * 64 + oo);
      v1 = *(const uint4*)(x + (size_t)n1 * 64 + oo);
      v2 = *(const uint4*)(x + (size_t)n2 * 64 + oo);
      v3 = *(const uint4*)(x + (size_t)n3 * 64 + oo);
    }
    ACCM(v0,  0) ACCM(v1,  8) ACCM(v2, 16) ACCM(v3, 24)
  } else {
    uint4 v0, v1, v2, v3, v4, v5;
    {
      int j0 = min( 0 + q, cm1), j1 = min( 8 + q, cm1), j2 = min(16 + q, cm1);
      int j3 = min(24 + q, cm1), j4 = min(32 + q, cm1), j5 = min(40 + q, cm1);
      int n0 = __shfl(nb_l, j0), n1 = __shfl(nb_l, j1), n2 = __shfl(nb_l, j2);
      int n3 = __shfl(nb_l, j3), n4 = __shfl(nb_l, j4), n5 = __shfl(nb_l, j5);
      v0 = *(const uint4*)(x + (size_t)n0 * 64 + oo);
      v1 = *(const uint4*)(x + (size_t)n1 * 64 + oo);
      v2 = *(const uint4*)(x + (size_t)n2 * 64 + oo);
      v3 = *(const uint4*)(x + (size_t)n3 * 64 + oo);
      v4 = *(const uint4*)(x + (size_t)n4 * 64 + oo);
      v5 = *(const uint4*)(x + (size_t)n5 * 64 + oo);
    }
    ACCM(v0,  0) ACCM(v1,  8) ACCM(v2, 16)
    ACCM(v3, 24) ACCM(v4, 32) ACCM(v5, 40)
    for (int i = 48 + q; i < cnt; i += 8){
      int nb = ssrc[s + i];
      uint4 vv = *(const uint4*)(x + (size_t)nb * 64 + oo);
      add2(a0,a1,vv.x); add2(a2,a3,vv.y); add2(a4,a5,vv.z); add2(a6,a7,vv.w);
    }
  }
  #undef ACCM
  for (int m = 8; m < 64; m <<= 1){
    a0 += __shfl_xor(a0, m); a1 += __shfl_xor(a1, m);
    a2 += __shfl_xor(a2, m); a3 += __shfl_xor(a3, m);
    a4 += __shfl_xor(a4, m); a5 += __shfl_xor(a5, m);
    a6 += __shfl_xor(a6, m); a7 += __shfl_xor(a7, m);
  }
  if (lane < 8){
    uint4 pkd;
    pkd.x = (unsigned)f2bf(a0) | ((unsigned)f2bf(a1) << 16);
    pkd.y = (unsigned)f2bf(a2) | ((unsigned)f2bf(a3) << 16);
    pkd.z = (unsigned)f2bf(a4) | ((unsigned)f2bf(a5) << 16);
    pkd.w = (unsigned)f2bf(a6) | ((unsigned)f2bf(a7) << 16);
    *(uint4*)&aggL[w][lane * 8] = pkd;
  }
  __syncthreads();
  if (w == 0){
    // D[ch_out][node] = sum_k W[k][ch_out] * agg[node][k]; A=W-frag, B=agg.
    int r = lane & 15, g = lane >> 4;
    const short8* Wf = (const short8*)Wfrag;
    const short8 B0 = *(const short8*)&aggL[r][g * 8];
    const short8 B1 = *(const short8*)&aggL[r][32 + g * 8];
    #pragma unroll
    for (int mb = 0; mb < 4; ++mb){
      f32x4 c = {0.f, 0.f, 0.f, 0.f};
      c = __builtin_amdgcn_mfma_f32_16x16x32_bf16(Wf[(mb * 2 + 0) * 64 + lane], B0, c, 0, 0, 0);
      c = __builtin_amdgcn_mfma_f32_16x16x32_bf16(Wf[(mb * 2 + 1) * 64 + lane], B1, c, 0, 0, 0);
      const float4 bb = *(const float4*)(b + mb * 16 + g * 4);
      float y0 = c[0] + bb.x, y1 = c[1] + bb.y, y2 = c[2] + bb.z, y3 = c[3] + bb.w;
      y0 = (y0 > 0.f) ? y0 : SLOPE * y0;
      y1 = (y1 > 0.f) ? y1 : SLOPE * y1;
      y2 = (y2 > 0.f) ? y2 : SLOPE * y2;
      y3 = (y3 > 0.f) ? y3 : SLOPE * y3;
      ushort4 pk4;
      pk4.x = f2bf(y0); pk4.y = f2bf(y1); pk4.z = f2bf(y2); pk4.w = f2bf(y3);
      *(ushort4*)(out + (size_t)(blockIdx.x * 16 + r) * 64 + mb * 16 + g * 4) = pk4;
    }
  }
}

// ---------------- Last layer: y4 = x @ W5 [N,4] (w=0), then agg + b5 ----------------
__global__ void premult_k(const unsigned short* __restrict__ x, const float* __restrict__ W5,
                          float* __restrict__ y4){
  int gt = blockIdx.x * 256 + threadIdx.x;
  int node = gt >> 6;
  int lane = threadIdx.x & 63;
  float xv = bf2f(x[node * 64 + lane]);
  float p0 = xv * W5[lane * 3 + 0];
  float p1 = xv * W5[lane * 3 + 1];
  float p2 = xv * W5[lane * 3 + 2];
  for (int m = 1; m < 64; m <<= 1){
    p0 += __shfl_xor(p0, m);
    p1 += __shfl_xor(p1, m);
    p2 += __shfl_xor(p2, m);
  }
  if (lane == 0){
    float4 v; v.x = p0; v.y = p1; v.z = p2; v.w = 0.f;
    *(float4*)(y4 + (size_t)node * 4) = v;
  }
}

__global__ void agg3_k(const float* __restrict__ y4, const int* __restrict__ row_ptr,
                       const int* __restrict__ ssrc, const float* __restrict__ b5,
                       float* __restrict__ out){
  int gt = blockIdx.x * 256 + threadIdx.x;
  int node = gt >> 6;
  int lane = threadIdx.x & 63;
  int s = row_ptr[node], t = row_ptr[node + 1];
  int c = lane & 3;
  float acc = 0.f;
  for (int i = s + (lane >> 2); i < t; i += 16) acc += y4[(size_t)ssrc[i] * 4 + c];
  for (int m = 4; m < 64; m <<= 1) acc += __shfl_xor(acc, m);
  if (lane < 3) out[node * 3 + lane] = acc + b5[lane];
}

// ---------------- launch ----------------

extern "C" void kernel_launch(void* const* d_in, const int* in_sizes, int n_in,
                              void* d_out, int out_size, void* d_ws, size_t ws_size,
                              hipStream_t stream){
  const float* feat = (const float*)d_in[0];
  const int*   src  = (const int*)d_in[1];
  const int*   dst  = (const int*)d_in[2];
  const float* W1   = (const float*)d_in[3];
  const float* b1   = (const float*)d_in[4];
  const float* W2   = (const float*)d_in[5];
  const float* b2   = (const float*)d_in[6];
  const float* W5   = (const float*)d_in[7];
  const float* b5   = (const float*)d_in[8];
  float* out = (float*)d_out;

  char* p = (char*)d_ws;
  auto carve = [&](size_t bytes) -> char* {
    char* r = p; p += align_up(bytes, 512); return r;
  };
  int*   row_ptr = (int*)carve((size_t)(N_NODES + 1) * 4);
  int*   bsums   = (int*)carve(512 * 4);
  unsigned short* Wfrag = (unsigned short*)carve(4096 * 2);
  int*   ghist   = (int*)carve((size_t)NGH * 4);
  int*   goff    = (int*)carve((size_t)NGH * 4);
  int*   ssrc    = (int*)carve(((size_t)N_EDGES + 64) * 4);  // +64 margin
  unsigned short* bufA = (unsigned short*)carve((size_t)N_NODES * 64 * 2);
  unsigned short* bufB = (unsigned short*)carve((size_t)N_NODES * 64 * 2);
  float* y4      = (float*)carve((size_t)N_NODES * 4 * 4);
  int*   pk      = (int*)carve((size_t)N_EDGES * 4);

  // ---- CSR build ----
  gbhist_k<<<NBLK_B, 1024, 0, stream>>>(dst, ghist);
  {
    int nb = (NGH + 1023) / 1024;  // 98
    scan1_k<<<nb, 256, 0, stream>>>(ghist, goff, bsums, NGH);
    scan2_k<<<1, 64, 0, stream>>>(bsums, nb);
    scan3_k<<<(NGH + 255) / 256, 256, 0, stream>>>(goff, bsums, NGH);
  }
  passB_k<<<NBLK_B, 1024, 0, stream>>>(src, dst, ghist, goff, pk);
  passC_k<<<NBUCK, 512, 0, stream>>>(pk, goff, ssrc, row_ptr);
  hipMemsetAsync(ssrc + N_EDGES, 0, 64 * 4, stream);
  wfrag_k<<<1, 64, 0, stream>>>(W2, Wfrag);

  // ---- layers ----
  conv1_k<<<(N_NODES * 64) / 256, 256, 0, stream>>>(feat, row_ptr, ssrc, W1, b1, bufA);

  unsigned short* xin = bufA;
  unsigned short* xout = bufB;
  for (int l = 0; l < 7; ++l){
    aggmm_k<<<N_NODES / 16, 1024, 0, stream>>>(xin, row_ptr, ssrc, Wfrag, b2, xout);
    unsigned short* tmp = xin; xin = xout; xout = tmp;
  }

  premult_k<<<(N_NODES * 64) / 256, 256, 0, stream>>>(xin, W5, y4);
  agg3_k<<<(N_NODES * 64) / 256, 256, 0, stream>>>(y4, row_ptr, ssrc, b5, out);
}